// Round 1
// baseline (588.137 us; speedup 1.0000x reference)
//
#include <hip/hip_runtime.h>
#include <hip/hip_bf16.h>
#include <cstdint>

#define N_TOK 4096
#define DIM   1024
#define NEXP  8
#define FDIM  2048
#define LDK   40   // padded LDS K-stride (elements); 80B row stride, 16B aligned

typedef _Float16 f16_t;
typedef _Float16 f16x8 __attribute__((ext_vector_type(8)));
typedef float    f32x4 __attribute__((ext_vector_type(4)));

__device__ inline unsigned packh(float a, float b) {
    union { f16_t h[2]; unsigned u; } p;
    p.h[0] = (f16_t)a; p.h[1] = (f16_t)b;
    return p.u;
}

// ---------------- Router: fp32 logits -> softmax -> top2 -> renorm -> buckets ----------------
__global__ __launch_bounds__(256) void router_kernel(
    const float* __restrict__ x, const float* __restrict__ wr,
    float* __restrict__ topw, int* __restrict__ counts, int* __restrict__ bucket)
{
    __shared__ float r[NEXP][DIM];   // router transposed, 32 KB
    int tid = threadIdx.x;
    for (int i = tid; i < DIM * NEXP / 4; i += 256) {
        float4 v = ((const float4*)wr)[i];
        int base = i * 4;                    // flat = d*8 + e
        r[(base + 0) & 7][(base + 0) >> 3] = v.x;
        r[(base + 1) & 7][(base + 1) >> 3] = v.y;
        r[(base + 2) & 7][(base + 2) >> 3] = v.z;
        r[(base + 3) & 7][(base + 3) >> 3] = v.w;
    }
    __syncthreads();
    int wave = tid >> 6, lane = tid & 63;
    int t0 = blockIdx.x * 16 + wave * 4;
    for (int tt = 0; tt < 4; ++tt) {
        int t = t0 + tt;
        float acc[NEXP];
#pragma unroll
        for (int e = 0; e < NEXP; e++) acc[e] = 0.f;
        const float* xr = x + (size_t)t * DIM;
        for (int d = lane; d < DIM; d += 64) {
            float xv = xr[d];
#pragma unroll
            for (int e = 0; e < NEXP; e++) acc[e] += xv * r[e][d];
        }
#pragma unroll
        for (int e = 0; e < NEXP; e++) {
#pragma unroll
            for (int off = 32; off > 0; off >>= 1)
                acc[e] += __shfl_xor(acc[e], off, 64);
        }
        if (lane == 0) {
            float mx = acc[0];
#pragma unroll
            for (int e = 1; e < NEXP; e++) mx = fmaxf(mx, acc[e]);
            float p[NEXP]; float s = 0.f;
#pragma unroll
            for (int e = 0; e < NEXP; e++) { p[e] = expf(acc[e] - mx); s += p[e]; }
            float inv = 1.f / s;
#pragma unroll
            for (int e = 0; e < NEXP; e++) p[e] *= inv;
            int i1 = 0; float p1 = p[0];
#pragma unroll
            for (int e = 1; e < NEXP; e++) if (p[e] > p1) { p1 = p[e]; i1 = e; }
            int i2 = -1; float p2 = -1.f;
#pragma unroll
            for (int e = 0; e < NEXP; e++) if (e != i1 && p[e] > p2) { p2 = p[e]; i2 = e; }
            float e2 = expf(p2 - p1);          // renorm softmax over (p1,p2)
            float w1 = 1.f / (1.f + e2);
            topw[t * 2 + 0] = w1;
            topw[t * 2 + 1] = e2 * w1;
            int pos1 = atomicAdd(&counts[i1], 1);
            bucket[i1 * N_TOK + pos1] = t * 2 + 0;
            int pos2 = atomicAdd(&counts[i2], 1);
            bucket[i2 * N_TOK + pos2] = t * 2 + 1;
        }
    }
}

// ---------------- Stage A: H[ent,f] = silu(x@Wg) * (x@Wu), gathered rows, f16 MFMA ----------------
// BM=128, BN=64 (per weight), BK=32. 4 waves in 2x2; wave tile: 64m x 32n for both G and U.
__global__ __launch_bounds__(256) void gateup_kernel(
    const float* __restrict__ x,
    const float* __restrict__ wg, const float* __restrict__ wu,
    const int* __restrict__ counts, const int* __restrict__ bucket,
    f16_t* __restrict__ H)
{
    int e = blockIdx.z;
    int cnt = counts[e];
    int m0 = blockIdx.y * 128;
    if (m0 >= cnt) return;
    int n0 = blockIdx.x * 64;

    __shared__ f16_t sA[128 * LDK];
    __shared__ f16_t sBg[64 * LDK];
    __shared__ f16_t sBu[64 * LDK];
    __shared__ int sEnt[128];

    int tid = threadIdx.x;
    if (tid < 128) {
        int i = m0 + tid;
        sEnt[tid] = bucket[e * N_TOK + (i < cnt ? i : m0)];
    }
    __syncthreads();

    int arow = tid >> 3;            // 0..31
    int acol = (tid & 7) * 4;       // 0..28
    int bkp  = (tid >> 4) * 2;      // 0..30 even
    int bn4  = (tid & 15) * 4;      // 0..60
    const float* gb = wg + (size_t)e * DIM * FDIM + n0;
    const float* ub = wu + (size_t)e * DIM * FDIM + n0;

    f32x4 accG[4][2], accU[4][2];
    f32x4 zero = {0.f, 0.f, 0.f, 0.f};
#pragma unroll
    for (int i = 0; i < 4; i++)
#pragma unroll
        for (int j = 0; j < 2; j++) { accG[i][j] = zero; accU[i][j] = zero; }

    int wave = tid >> 6, lane = tid & 63;
    int wm = (wave & 1) * 64, wn = (wave >> 1) * 32;
    int fm = lane & 15, fq = (lane >> 4) * 8;

    for (int k0 = 0; k0 < DIM; k0 += 32) {
        // stage x rows (fp32 -> f16)
#pragma unroll
        for (int p = 0; p < 4; ++p) {
            int r = arow + p * 32;
            int t = sEnt[r] >> 1;
            float4 v = *(const float4*)(x + (size_t)t * DIM + k0 + acol);
            union { f16_t h[4]; uint2 u; } pk;
            pk.h[0] = (f16_t)v.x; pk.h[1] = (f16_t)v.y; pk.h[2] = (f16_t)v.z; pk.h[3] = (f16_t)v.w;
            *(uint2*)&sA[r * LDK + acol] = pk.u;
        }
        // stage Wg / Wu tiles, transposed [n][k], fp32 -> f16 pairs
        {
            const float* g0 = gb + (size_t)(k0 + bkp) * FDIM + bn4;
            float4 v0 = *(const float4*)g0;
            float4 v1 = *(const float4*)(g0 + FDIM);
            *(unsigned*)&sBg[(bn4 + 0) * LDK + bkp] = packh(v0.x, v1.x);
            *(unsigned*)&sBg[(bn4 + 1) * LDK + bkp] = packh(v0.y, v1.y);
            *(unsigned*)&sBg[(bn4 + 2) * LDK + bkp] = packh(v0.z, v1.z);
            *(unsigned*)&sBg[(bn4 + 3) * LDK + bkp] = packh(v0.w, v1.w);
            const float* u0 = ub + (size_t)(k0 + bkp) * FDIM + bn4;
            float4 w0 = *(const float4*)u0;
            float4 w1 = *(const float4*)(u0 + FDIM);
            *(unsigned*)&sBu[(bn4 + 0) * LDK + bkp] = packh(w0.x, w1.x);
            *(unsigned*)&sBu[(bn4 + 1) * LDK + bkp] = packh(w0.y, w1.y);
            *(unsigned*)&sBu[(bn4 + 2) * LDK + bkp] = packh(w0.z, w1.z);
            *(unsigned*)&sBu[(bn4 + 3) * LDK + bkp] = packh(w0.w, w1.w);
        }
        __syncthreads();
        f16x8 af[4], bg[2], bu[2];
#pragma unroll
        for (int mi = 0; mi < 4; mi++)
            af[mi] = *(const f16x8*)&sA[(wm + mi * 16 + fm) * LDK + fq];
#pragma unroll
        for (int ni = 0; ni < 2; ni++) {
            bg[ni] = *(const f16x8*)&sBg[(wn + ni * 16 + fm) * LDK + fq];
            bu[ni] = *(const f16x8*)&sBu[(wn + ni * 16 + fm) * LDK + fq];
        }
#pragma unroll
        for (int mi = 0; mi < 4; mi++)
#pragma unroll
            for (int ni = 0; ni < 2; ni++) {
                accG[mi][ni] = __builtin_amdgcn_mfma_f32_16x16x32_f16(af[mi], bg[ni], accG[mi][ni], 0, 0, 0);
                accU[mi][ni] = __builtin_amdgcn_mfma_f32_16x16x32_f16(af[mi], bu[ni], accU[mi][ni], 0, 0, 0);
            }
        __syncthreads();
    }
    // epilogue: silu(G)*U -> H (f16). C/D layout: col=lane&15, row=(lane>>4)*4+i
    int crow = (lane >> 4) * 4, ccol = lane & 15;
#pragma unroll
    for (int mi = 0; mi < 4; mi++) {
#pragma unroll
        for (int i = 0; i < 4; i++) {
            int m = wm + mi * 16 + crow + i;
            if (m0 + m < cnt) {
                int ent = sEnt[m];
                f16_t* hr = H + (size_t)ent * FDIM + n0 + wn;
#pragma unroll
                for (int ni = 0; ni < 2; ni++) {
                    float g = accG[mi][ni][i], u = accU[mi][ni][i];
                    float h = (g / (1.f + __expf(-g))) * u;
                    hr[ni * 16 + ccol] = (f16_t)h;
                }
            }
        }
    }
}

// ---------------- Stage B: Y[ent,d] = w[ent] * (H[ent,:] @ Wd), m97-shape 128x128 ----------------
__global__ __launch_bounds__(256) void down_kernel(
    const f16_t* __restrict__ H, const float* __restrict__ wd,
    const int* __restrict__ counts, const int* __restrict__ bucket,
    const float* __restrict__ topw, float* __restrict__ Y)
{
    int e = blockIdx.z;
    int cnt = counts[e];
    int m0 = blockIdx.y * 128;
    if (m0 >= cnt) return;
    int n0 = blockIdx.x * 128;

    __shared__ f16_t sA[128 * LDK];
    __shared__ f16_t sB[128 * LDK];
    __shared__ int sEnt[128];

    int tid = threadIdx.x;
    if (tid < 128) {
        int i = m0 + tid;
        sEnt[tid] = bucket[e * N_TOK + (i < cnt ? i : m0)];
    }
    __syncthreads();

    int arow = tid >> 2;            // 0..63
    int acol = (tid & 3) * 8;       // 0,8,16,24
    int bkp  = (tid >> 5) * 2;      // 0..14 even
    int bn4  = (tid & 31) * 4;      // 0..124
    const float* wb = wd + (size_t)e * FDIM * DIM + n0;

    f32x4 acc[4][4];
    f32x4 zero = {0.f, 0.f, 0.f, 0.f};
#pragma unroll
    for (int i = 0; i < 4; i++)
#pragma unroll
        for (int j = 0; j < 4; j++) acc[i][j] = zero;

    int wave = tid >> 6, lane = tid & 63;
    int wm = (wave & 1) * 64, wn = (wave >> 1) * 64;
    int fm = lane & 15, fq = (lane >> 4) * 8;

    for (int k0 = 0; k0 < FDIM; k0 += 32) {
        // stage H rows (already f16): 16B per thread, 2 row-passes
#pragma unroll
        for (int p = 0; p < 2; ++p) {
            int r = arow + p * 64;
            int ent = sEnt[r];
            uint4 v = *(const uint4*)(H + (size_t)ent * FDIM + k0 + acol);
            *(uint4*)&sA[r * LDK + acol] = v;
        }
        // stage Wd transposed [n][k], fp32 -> f16 pairs, 2 k-passes
#pragma unroll
        for (int p = 0; p < 2; ++p) {
            int k = bkp + p * 16;
            const float* g0 = wb + (size_t)(k0 + k) * DIM + bn4;
            float4 v0 = *(const float4*)g0;
            float4 v1 = *(const float4*)(g0 + DIM);
            *(unsigned*)&sB[(bn4 + 0) * LDK + k] = packh(v0.x, v1.x);
            *(unsigned*)&sB[(bn4 + 1) * LDK + k] = packh(v0.y, v1.y);
            *(unsigned*)&sB[(bn4 + 2) * LDK + k] = packh(v0.z, v1.z);
            *(unsigned*)&sB[(bn4 + 3) * LDK + k] = packh(v0.w, v1.w);
        }
        __syncthreads();
        f16x8 af[4], bf[4];
#pragma unroll
        for (int mi = 0; mi < 4; mi++)
            af[mi] = *(const f16x8*)&sA[(wm + mi * 16 + fm) * LDK + fq];
#pragma unroll
        for (int ni = 0; ni < 4; ni++)
            bf[ni] = *(const f16x8*)&sB[(wn + ni * 16 + fm) * LDK + fq];
#pragma unroll
        for (int mi = 0; mi < 4; mi++)
#pragma unroll
            for (int ni = 0; ni < 4; ni++)
                acc[mi][ni] = __builtin_amdgcn_mfma_f32_16x16x32_f16(af[mi], bf[ni], acc[mi][ni], 0, 0, 0);
        __syncthreads();
    }
    int crow = (lane >> 4) * 4, ccol = lane & 15;
#pragma unroll
    for (int mi = 0; mi < 4; mi++) {
#pragma unroll
        for (int i = 0; i < 4; i++) {
            int m = wm + mi * 16 + crow + i;
            if (m0 + m < cnt) {
                int ent = sEnt[m];
                float w = topw[ent];
                float* yr = Y + (size_t)ent * DIM + n0 + wn;
#pragma unroll
                for (int ni = 0; ni < 4; ni++)
                    yr[ni * 16 + ccol] = w * acc[mi][ni][i];
            }
        }
    }
}

// ---------------- Combine: out[t] = Y[2t] + Y[2t+1] ----------------
__global__ __launch_bounds__(256) void combine_kernel(
    const float* __restrict__ Y, float* __restrict__ out)
{
    int i = blockIdx.x * 256 + threadIdx.x;   // float4 index over [N_TOK][DIM/4]
    int t = i >> 8;
    int c = i & 255;
    float4 a = ((const float4*)Y)[(size_t)(2 * t) * 256 + c];
    float4 b = ((const float4*)Y)[(size_t)(2 * t + 1) * 256 + c];
    float4 o;
    o.x = a.x + b.x; o.y = a.y + b.y; o.z = a.z + b.z; o.w = a.w + b.w;
    ((float4*)out)[i] = o;
}

extern "C" void kernel_launch(void* const* d_in, const int* in_sizes, int n_in,
                              void* d_out, int out_size, void* d_ws, size_t ws_size,
                              hipStream_t stream) {
    const float* x  = (const float*)d_in[0];
    const float* wr = (const float*)d_in[1];
    const float* wg = (const float*)d_in[2];
    const float* wu = (const float*)d_in[3];
    const float* wd = (const float*)d_in[4];
    float* out = (float*)d_out;
    char* ws = (char*)d_ws;

    int*   counts = (int*)ws;                       // 32 B (zeroed)
    int*   bucket = (int*)(ws + 1024);              // 128 KB
    float* topw   = (float*)(ws + 256 * 1024);      // 32 KB
    f16_t* H      = (f16_t*)(ws + (1ull << 20));    // 32 MB
    float* Y      = (float*)(ws + (34ull << 20));   // 32 MB

    hipMemsetAsync(counts, 0, 1024, stream);
    router_kernel<<<256, 256, 0, stream>>>(x, wr, topw, counts, bucket);
    gateup_kernel<<<dim3(32, 32, 8), 256, 0, stream>>>(x, wg, wu, counts, bucket, H);
    down_kernel<<<dim3(8, 32, 8), 256, 0, stream>>>(H, wd, counts, bucket, topw, Y);
    combine_kernel<<<4096, 256, 0, stream>>>(Y, out);
}

// Round 2
// 502.614 us; speedup vs baseline: 1.1702x; 1.1702x over previous
//
#include <hip/hip_runtime.h>
#include <cstdint>

#define N_TOK 4096
#define DIM   1024
#define NEXP  8
#define FDIM  2048

typedef _Float16 f16_t;
typedef _Float16 f16x8 __attribute__((ext_vector_type(8)));
typedef float    f32x4 __attribute__((ext_vector_type(4)));

__device__ inline unsigned packh(float a, float b) {
    union { f16_t h[2]; unsigned u; } p;
    p.h[0] = (f16_t)a; p.h[1] = (f16_t)b;
    return p.u;
}

// async global->LDS, 16B per lane; LDS dest must be base + lane*16 (it is, by construction)
__device__ inline void gl2lds16(const void* g, void* l) {
    __builtin_amdgcn_global_load_lds(
        (const __attribute__((address_space(1))) unsigned*)g,
        (__attribute__((address_space(3))) unsigned*)l, 16, 0, 0);
}

// ---------------- Router: fp32 logits -> softmax -> top2 -> renorm -> buckets ----------------
__global__ __launch_bounds__(256) void router_kernel(
    const float* __restrict__ x, const float* __restrict__ wr,
    float* __restrict__ topw, int* __restrict__ counts, int* __restrict__ bucket)
{
    __shared__ float r[NEXP][DIM];   // router transposed, 32 KB
    int tid = threadIdx.x;
    for (int i = tid; i < DIM * NEXP / 4; i += 256) {
        float4 v = ((const float4*)wr)[i];
        int base = i * 4;                    // flat = d*8 + e
        r[(base + 0) & 7][(base + 0) >> 3] = v.x;
        r[(base + 1) & 7][(base + 1) >> 3] = v.y;
        r[(base + 2) & 7][(base + 2) >> 3] = v.z;
        r[(base + 3) & 7][(base + 3) >> 3] = v.w;
    }
    __syncthreads();
    int wave = tid >> 6, lane = tid & 63;
    int t0 = blockIdx.x * 16 + wave * 4;
    for (int tt = 0; tt < 4; ++tt) {
        int t = t0 + tt;
        float acc[NEXP];
#pragma unroll
        for (int e = 0; e < NEXP; e++) acc[e] = 0.f;
        const float* xr = x + (size_t)t * DIM;
        for (int d = lane; d < DIM; d += 64) {
            float xv = xr[d];
#pragma unroll
            for (int e = 0; e < NEXP; e++) acc[e] += xv * r[e][d];
        }
#pragma unroll
        for (int e = 0; e < NEXP; e++) {
#pragma unroll
            for (int off = 32; off > 0; off >>= 1)
                acc[e] += __shfl_xor(acc[e], off, 64);
        }
        if (lane == 0) {
            float mx = acc[0];
#pragma unroll
            for (int e = 1; e < NEXP; e++) mx = fmaxf(mx, acc[e]);
            float p[NEXP]; float s = 0.f;
#pragma unroll
            for (int e = 0; e < NEXP; e++) { p[e] = expf(acc[e] - mx); s += p[e]; }
            float inv = 1.f / s;
#pragma unroll
            for (int e = 0; e < NEXP; e++) p[e] *= inv;
            int i1 = 0; float p1 = p[0];
#pragma unroll
            for (int e = 1; e < NEXP; e++) if (p[e] > p1) { p1 = p[e]; i1 = e; }
            int i2 = -1; float p2 = -1.f;
#pragma unroll
            for (int e = 0; e < NEXP; e++) if (e != i1 && p[e] > p2) { p2 = p[e]; i2 = e; }
            float e2 = expf(p2 - p1);          // renorm softmax over (p1,p2)
            float w1 = 1.f / (1.f + e2);
            topw[t * 2 + 0] = w1;
            topw[t * 2 + 1] = e2 * w1;
            int pos1 = atomicAdd(&counts[i1], 1);
            bucket[i1 * N_TOK + pos1] = t * 2 + 0;
            int pos2 = atomicAdd(&counts[i2], 1);
            bucket[i2 * N_TOK + pos2] = t * 2 + 1;
        }
    }
}

// ---------------- x: fp32 -> f16 ----------------
__global__ __launch_bounds__(256) void xcast_kernel(const float* __restrict__ x, f16_t* __restrict__ xf)
{
    int i = blockIdx.x * 256 + threadIdx.x;   // 8 elements per thread
    float4 a = ((const float4*)x)[2 * i];
    float4 b = ((const float4*)x)[2 * i + 1];
    union { f16_t h[8]; uint4 u; } p;
    p.h[0] = (f16_t)a.x; p.h[1] = (f16_t)a.y; p.h[2] = (f16_t)a.z; p.h[3] = (f16_t)a.w;
    p.h[4] = (f16_t)b.x; p.h[5] = (f16_t)b.y; p.h[6] = (f16_t)b.z; p.h[7] = (f16_t)b.w;
    ((uint4*)xf)[i] = p.u;
}

// ---------------- Weight transpose+convert: in [R][C] fp32 -> out [C][R] f16 ----------------
// tile = 128 (R) x 64 (C). Pair trick: u32 = (f16 of row 2dp, f16 of row 2dp+1) -> b32 LDS ops only.
__global__ __launch_bounds__(256) void transpose_cvt(
    const float* __restrict__ inA, const float* __restrict__ inB,
    f16_t* __restrict__ outA, f16_t* __restrict__ outB,
    int R, int C, int tiles_r, int nA)
{
    __shared__ unsigned sP[64][68];    // [col][row-pair], pad 68 keeps phase-2 b128 16B-aligned
    int m = blockIdx.y;
    const float* in; f16_t* out;
    if (m < nA) { in = inA + (size_t)m * DIM * FDIM; out = outA + (size_t)m * DIM * FDIM; }
    else        { in = inB + (size_t)(m - nA) * DIM * FDIM; out = outB + (size_t)(m - nA) * DIM * FDIM; }
    int tix = blockIdx.x;
    int rb = (tix % tiles_r) * 128;
    int cb = (tix / tiles_r) * 64;
    int t = threadIdx.x;
    // phase 1: read 2 rows x 16 cols, pack pairs, write LDS transposed
    int dp = t >> 2;              // row-pair 0..63
    int fc = (t & 3) * 16;        // col chunk
    const float* r0 = in + (size_t)(rb + 2 * dp) * C + cb + fc;
    const float* r1 = r0 + C;
#pragma unroll
    for (int j = 0; j < 16; j += 4) {
        float4 a = *(const float4*)(r0 + j);
        float4 b = *(const float4*)(r1 + j);
        sP[fc + j + 0][dp] = packh(a.x, b.x);
        sP[fc + j + 1][dp] = packh(a.y, b.y);
        sP[fc + j + 2][dp] = packh(a.z, b.z);
        sP[fc + j + 3][dp] = packh(a.w, b.w);
    }
    __syncthreads();
    // phase 2: each thread writes 32 contiguous f16 of one out-row
    int c = t >> 2;
    int rc = t & 3;
    uint4* dst = (uint4*)(out + (size_t)(cb + c) * R + rb + rc * 32);
    const unsigned* src = &sP[c][rc * 16];
#pragma unroll
    for (int j = 0; j < 4; j++)
        dst[j] = *(const uint4*)(src + j * 4);
}

// ---------------- Stage A: H = silu(x@Wg) * (x@Wu); all-f16, global_load_lds staging ----------------
// BM=128, BN=64 per weight, BK=32. LDS rows = 32 f16 = 4 chunks of 16B, chunk q of row r at pos (q+(r>>1))&3.
__global__ __launch_bounds__(256) void gateup_kernel(
    const f16_t* __restrict__ xf,
    const f16_t* __restrict__ wgT, const f16_t* __restrict__ wuT,
    const int* __restrict__ counts, const int* __restrict__ bucket,
    f16_t* __restrict__ H)
{
    int e = blockIdx.z;
    int cnt = counts[e];
    int m0 = blockIdx.y * 128;
    if (m0 >= cnt) return;
    int n0 = blockIdx.x * 64;

    __shared__ f16_t sA[128 * 32];
    __shared__ f16_t sBg[64 * 32];
    __shared__ f16_t sBu[64 * 32];
    __shared__ int sEnt[128];

    int tid = threadIdx.x;
    if (tid < 128) {
        int i = m0 + tid;
        sEnt[tid] = bucket[e * N_TOK + (i < cnt ? i : m0)];
    }
    __syncthreads();

    int wave = tid >> 6, lane = tid & 63;
    int q = ((lane & 3) - (lane >> 3)) & 3;     // global-side chunk swizzle
    int rA0 = wave * 32 + (lane >> 2);
    int rA1 = rA0 + 16;
    int rB  = wave * 16 + (lane >> 2);
    const f16_t* gA0 = xf + (size_t)(sEnt[rA0] >> 1) * DIM + q * 8;
    const f16_t* gA1 = xf + (size_t)(sEnt[rA1] >> 1) * DIM + q * 8;
    const f16_t* gBg = wgT + ((size_t)e * FDIM + n0 + rB) * DIM + q * 8;
    const f16_t* gBu = wuT + ((size_t)e * FDIM + n0 + rB) * DIM + q * 8;
    f16_t* lA0 = &sA[wave * 1024 + lane * 8];
    f16_t* lA1 = lA0 + 512;
    f16_t* lBg = &sBg[wave * 512 + lane * 8];
    f16_t* lBu = &sBu[wave * 512 + lane * 8];

    f32x4 accG[4][2], accU[4][2];
    f32x4 zero = {0.f, 0.f, 0.f, 0.f};
#pragma unroll
    for (int i = 0; i < 4; i++)
#pragma unroll
        for (int j = 0; j < 2; j++) { accG[i][j] = zero; accU[i][j] = zero; }

    int wm = (wave & 1) * 64, wn = (wave >> 1) * 32;
    int fm = lane & 15, quad = lane >> 4;
    int p8 = ((quad + (fm >> 1)) & 3) * 8;      // swizzled chunk offset for frag reads

    for (int k0 = 0; k0 < DIM; k0 += 32) {
        gl2lds16(gA0 + k0, lA0);
        gl2lds16(gA1 + k0, lA1);
        gl2lds16(gBg + k0, lBg);
        gl2lds16(gBu + k0, lBu);
        __syncthreads();
        f16x8 af[4], bg[2], bu[2];
#pragma unroll
        for (int mi = 0; mi < 4; mi++)
            af[mi] = *(const f16x8*)&sA[(wm + mi * 16 + fm) * 32 + p8];
#pragma unroll
        for (int ni = 0; ni < 2; ni++) {
            bg[ni] = *(const f16x8*)&sBg[(wn + ni * 16 + fm) * 32 + p8];
            bu[ni] = *(const f16x8*)&sBu[(wn + ni * 16 + fm) * 32 + p8];
        }
#pragma unroll
        for (int mi = 0; mi < 4; mi++)
#pragma unroll
            for (int ni = 0; ni < 2; ni++) {
                accG[mi][ni] = __builtin_amdgcn_mfma_f32_16x16x32_f16(af[mi], bg[ni], accG[mi][ni], 0, 0, 0);
                accU[mi][ni] = __builtin_amdgcn_mfma_f32_16x16x32_f16(af[mi], bu[ni], accU[mi][ni], 0, 0, 0);
            }
        __syncthreads();
    }
    // epilogue: silu(G)*U -> H. C/D layout: col=lane&15, row=(lane>>4)*4+i
    int crow = quad * 4, ccol = fm;
#pragma unroll
    for (int mi = 0; mi < 4; mi++) {
#pragma unroll
        for (int i = 0; i < 4; i++) {
            int m = wm + mi * 16 + crow + i;
            if (m0 + m < cnt) {
                int ent = sEnt[m];
                f16_t* hr = H + (size_t)ent * FDIM + n0 + wn;
#pragma unroll
                for (int ni = 0; ni < 2; ni++) {
                    float g = accG[mi][ni][i], u = accU[mi][ni][i];
                    float h = (g / (1.f + __expf(-g))) * u;
                    hr[ni * 16 + ccol] = (f16_t)h;
                }
            }
        }
    }
}

// ---------------- Stage B: Y[ent,d] = w[ent] * (H[ent,:] @ Wd); 128x128, global_load_lds staging ----------------
__global__ __launch_bounds__(256) void down_kernel(
    const f16_t* __restrict__ H, const f16_t* __restrict__ wdT,
    const int* __restrict__ counts, const int* __restrict__ bucket,
    const float* __restrict__ topw, float* __restrict__ Y)
{
    int e = blockIdx.z;
    int cnt = counts[e];
    int m0 = blockIdx.y * 128;
    if (m0 >= cnt) return;
    int n0 = blockIdx.x * 128;

    __shared__ f16_t sA[128 * 32];
    __shared__ f16_t sB[128 * 32];
    __shared__ int sEnt[128];

    int tid = threadIdx.x;
    if (tid < 128) {
        int i = m0 + tid;
        sEnt[tid] = bucket[e * N_TOK + (i < cnt ? i : m0)];
    }
    __syncthreads();

    int wave = tid >> 6, lane = tid & 63;
    int q = ((lane & 3) - (lane >> 3)) & 3;
    int r0 = wave * 32 + (lane >> 2);
    int r1 = r0 + 16;
    const f16_t* gA0 = H + (size_t)sEnt[r0] * FDIM + q * 8;
    const f16_t* gA1 = H + (size_t)sEnt[r1] * FDIM + q * 8;
    const f16_t* gB0 = wdT + ((size_t)e * DIM + n0 + r0) * FDIM + q * 8;
    const f16_t* gB1 = wdT + ((size_t)e * DIM + n0 + r1) * FDIM + q * 8;
    f16_t* lA0 = &sA[wave * 1024 + lane * 8];
    f16_t* lA1 = lA0 + 512;
    f16_t* lB0 = &sB[wave * 1024 + lane * 8];
    f16_t* lB1 = lB0 + 512;

    f32x4 acc[4][4];
    f32x4 zero = {0.f, 0.f, 0.f, 0.f};
#pragma unroll
    for (int i = 0; i < 4; i++)
#pragma unroll
        for (int j = 0; j < 4; j++) acc[i][j] = zero;

    int wm = (wave & 1) * 64, wn = (wave >> 1) * 64;
    int fm = lane & 15, quad = lane >> 4;
    int p8 = ((quad + (fm >> 1)) & 3) * 8;

    for (int k0 = 0; k0 < FDIM; k0 += 32) {
        gl2lds16(gA0 + k0, lA0);
        gl2lds16(gA1 + k0, lA1);
        gl2lds16(gB0 + k0, lB0);
        gl2lds16(gB1 + k0, lB1);
        __syncthreads();
        f16x8 af[4], bf[4];
#pragma unroll
        for (int mi = 0; mi < 4; mi++)
            af[mi] = *(const f16x8*)&sA[(wm + mi * 16 + fm) * 32 + p8];
#pragma unroll
        for (int ni = 0; ni < 4; ni++)
            bf[ni] = *(const f16x8*)&sB[(wn + ni * 16 + fm) * 32 + p8];
#pragma unroll
        for (int mi = 0; mi < 4; mi++)
#pragma unroll
            for (int ni = 0; ni < 4; ni++)
                acc[mi][ni] = __builtin_amdgcn_mfma_f32_16x16x32_f16(af[mi], bf[ni], acc[mi][ni], 0, 0, 0);
        __syncthreads();
    }
    int crow = quad * 4, ccol = fm;
#pragma unroll
    for (int mi = 0; mi < 4; mi++) {
#pragma unroll
        for (int i = 0; i < 4; i++) {
            int m = wm + mi * 16 + crow + i;
            if (m0 + m < cnt) {
                int ent = sEnt[m];
                float w = topw[ent];
                float* yr = Y + (size_t)ent * DIM + n0 + wn;
#pragma unroll
                for (int ni = 0; ni < 4; ni++)
                    yr[ni * 16 + ccol] = w * acc[mi][ni][i];
            }
        }
    }
}

// ---------------- Combine: out[t] = Y[2t] + Y[2t+1] ----------------
__global__ __launch_bounds__(256) void combine_kernel(
    const float* __restrict__ Y, float* __restrict__ out)
{
    int i = blockIdx.x * 256 + threadIdx.x;   // float4 index over [N_TOK][DIM/4]
    int t = i >> 8;
    int c = i & 255;
    float4 a = ((const float4*)Y)[(size_t)(2 * t) * 256 + c];
    float4 b = ((const float4*)Y)[(size_t)(2 * t + 1) * 256 + c];
    float4 o;
    o.x = a.x + b.x; o.y = a.y + b.y; o.z = a.z + b.z; o.w = a.w + b.w;
    ((float4*)out)[i] = o;
}

extern "C" void kernel_launch(void* const* d_in, const int* in_sizes, int n_in,
                              void* d_out, int out_size, void* d_ws, size_t ws_size,
                              hipStream_t stream) {
    const float* x  = (const float*)d_in[0];
    const float* wr = (const float*)d_in[1];
    const float* wg = (const float*)d_in[2];
    const float* wu = (const float*)d_in[3];
    const float* wd = (const float*)d_in[4];
    float* out = (float*)d_out;
    char* ws = (char*)d_ws;
    const size_t MB = 1ull << 20;

    // liveness-aliased workspace plan (peak 105 MB):
    int*   counts = (int*)ws;                       // 1 KB
    int*   bucket = (int*)(ws + 1024);              // 128 KB
    float* topw   = (float*)(ws + 160 * 1024);      // 32 KB
    f16_t* xf     = (f16_t*)(ws + 1 * MB);          // 1..9 MB   (dead after gateup)
    f16_t* wgT    = (f16_t*)(ws + 9 * MB);          // 9..41 MB  (dead after gateup)
    f16_t* wuT    = (f16_t*)(ws + 41 * MB);         // 41..73 MB (dead after gateup)
    f16_t* H      = (f16_t*)(ws + 73 * MB);         // 73..105 MB
    f16_t* wdT    = (f16_t*)(ws + 1 * MB);          // alias 1..33 MB (written post-gateup)
    float* Y      = (float*)(ws + 33 * MB);         // alias 33..65 MB (written by down)

    hipMemsetAsync(counts, 0, 1024, stream);
    router_kernel<<<256, 256, 0, stream>>>(x, wr, topw, counts, bucket);
    xcast_kernel<<<2048, 256, 0, stream>>>(x, xf);
    // Wg, Wu: [1024][2048] -> [2048][1024]; 256 tiles each, 16 matrices
    transpose_cvt<<<dim3(256, 16), 256, 0, stream>>>(wg, wu, wgT, wuT, DIM, FDIM, DIM / 128, NEXP);
    gateup_kernel<<<dim3(FDIM / 64, 32, NEXP), 256, 0, stream>>>(xf, wgT, wuT, counts, bucket, H);
    // Wd: [2048][1024] -> [1024][2048]; 256 tiles, 8 matrices (into dead xf/wgT region)
    transpose_cvt<<<dim3(256, 8), 256, 0, stream>>>(wd, wd, wdT, wdT, FDIM, DIM, FDIM / 128, NEXP);
    down_kernel<<<dim3(DIM / 128, 32, NEXP), 256, 0, stream>>>(H, wdT, counts, bucket, topw, Y);
    combine_kernel<<<4096, 256, 0, stream>>>(Y, out);
}

// Round 3
// 416.129 us; speedup vs baseline: 1.4134x; 1.2078x over previous
//
#include <hip/hip_runtime.h>
#include <cstdint>

#define N_TOK 4096
#define DIM   1024
#define NEXP  8
#define FDIM  2048

typedef _Float16 f16_t;
typedef _Float16 f16x8 __attribute__((ext_vector_type(8)));
typedef float    f32x4 __attribute__((ext_vector_type(4)));

__device__ inline unsigned packh(float a, float b) {
    union { f16_t h[2]; unsigned u; } p;
    p.h[0] = (f16_t)a; p.h[1] = (f16_t)b;
    return p.u;
}

// async global->LDS, 16B per lane; LDS dest must be base + lane*16 (it is, by construction)
__device__ inline void gl2lds16(const void* g, void* l) {
    __builtin_amdgcn_global_load_lds(
        (const __attribute__((address_space(1))) unsigned*)g,
        (__attribute__((address_space(3))) unsigned*)l, 16, 0, 0);
}

// ---------------- Router: fp32 logits -> softmax -> top2 -> two-level scatter ----------------
// counts are padded to 128 B stride (counts[e*32]) to avoid same-line atomic serialization.
__global__ __launch_bounds__(256) void router_kernel(
    const float* __restrict__ x, const float* __restrict__ wr,
    float* __restrict__ topw, int* __restrict__ counts, int* __restrict__ bucket)
{
    __shared__ float r[NEXP][DIM];   // router transposed, 32 KB
    __shared__ int sIdx[32];         // per-block top2 expert ids, 2 per token
    int tid = threadIdx.x;
    for (int i = tid; i < DIM * NEXP / 4; i += 256) {
        float4 v = ((const float4*)wr)[i];
        int base = i * 4;                    // flat = d*8 + e
        r[(base + 0) & 7][(base + 0) >> 3] = v.x;
        r[(base + 1) & 7][(base + 1) >> 3] = v.y;
        r[(base + 2) & 7][(base + 2) >> 3] = v.z;
        r[(base + 3) & 7][(base + 3) >> 3] = v.w;
    }
    __syncthreads();
    int wave = tid >> 6, lane = tid & 63;
    int t0 = blockIdx.x * 16 + wave * 4;
    for (int tt = 0; tt < 4; ++tt) {
        int t = t0 + tt;
        float acc[NEXP];
#pragma unroll
        for (int e = 0; e < NEXP; e++) acc[e] = 0.f;
        const float* xr = x + (size_t)t * DIM;
#pragma unroll
        for (int k = 0; k < DIM / 64; k++) {
            int d = lane + k * 64;
            float xv = xr[d];
#pragma unroll
            for (int e = 0; e < NEXP; e++) acc[e] += xv * r[e][d];
        }
#pragma unroll
        for (int e = 0; e < NEXP; e++) {
#pragma unroll
            for (int off = 32; off > 0; off >>= 1)
                acc[e] += __shfl_xor(acc[e], off, 64);
        }
        if (lane == 0) {
            float mx = acc[0];
#pragma unroll
            for (int e = 1; e < NEXP; e++) mx = fmaxf(mx, acc[e]);
            float p[NEXP]; float s = 0.f;
#pragma unroll
            for (int e = 0; e < NEXP; e++) { p[e] = expf(acc[e] - mx); s += p[e]; }
            float inv = 1.f / s;
#pragma unroll
            for (int e = 0; e < NEXP; e++) p[e] *= inv;
            int i1 = 0; float p1 = p[0];
#pragma unroll
            for (int e = 1; e < NEXP; e++) if (p[e] > p1) { p1 = p[e]; i1 = e; }
            int i2 = -1; float p2 = -1.f;
#pragma unroll
            for (int e = 0; e < NEXP; e++) if (e != i1 && p[e] > p2) { p2 = p[e]; i2 = e; }
            float e2 = expf(p2 - p1);          // softmax over top-2 probs
            float w1 = 1.f / (1.f + e2);
            topw[t * 2 + 0] = w1;
            topw[t * 2 + 1] = e2 * w1;
            int j = (wave * 4 + tt) * 2;
            sIdx[j + 0] = i1;
            sIdx[j + 1] = i2;
        }
    }
    __syncthreads();
    // one lane per expert: count, reserve range with ONE atomic, scatter
    if (tid < NEXP) {
        int cnt = 0;
#pragma unroll
        for (int j = 0; j < 32; j++) cnt += (sIdx[j] == tid) ? 1 : 0;
        if (cnt > 0) {
            int pos = atomicAdd(&counts[tid * 32], cnt);
#pragma unroll
            for (int j = 0; j < 32; j++)
                if (sIdx[j] == tid)
                    bucket[tid * N_TOK + pos++] = (blockIdx.x * 16 + (j >> 1)) * 2 + (j & 1);
        }
    }
}

// ---------------- x: fp32 -> f16 ----------------
__global__ __launch_bounds__(256) void xcast_kernel(const float* __restrict__ x, f16_t* __restrict__ xf)
{
    int i = blockIdx.x * 256 + threadIdx.x;   // 8 elements per thread
    float4 a = ((const float4*)x)[2 * i];
    float4 b = ((const float4*)x)[2 * i + 1];
    union { f16_t h[8]; uint4 u; } p;
    p.h[0] = (f16_t)a.x; p.h[1] = (f16_t)a.y; p.h[2] = (f16_t)a.z; p.h[3] = (f16_t)a.w;
    p.h[4] = (f16_t)b.x; p.h[5] = (f16_t)b.y; p.h[6] = (f16_t)b.z; p.h[7] = (f16_t)b.w;
    ((uint4*)xf)[i] = p.u;
}

// ---------------- Weight transpose+convert: in [R][C] fp32 -> out [C][R] f16 ----------------
// tile = 128 (R) x 64 (C). Pair trick: u32 = (f16 of row 2dp, f16 of row 2dp+1) -> b32 LDS ops only.
__global__ __launch_bounds__(256) void transpose_cvt(
    const float* __restrict__ inA, const float* __restrict__ inB,
    f16_t* __restrict__ outA, f16_t* __restrict__ outB,
    int R, int C, int tiles_r, int nA)
{
    __shared__ unsigned sP[64][68];    // [col][row-pair], pad 68 keeps phase-2 b128 16B-aligned
    int m = blockIdx.y;
    const float* in; f16_t* out;
    if (m < nA) { in = inA + (size_t)m * DIM * FDIM; out = outA + (size_t)m * DIM * FDIM; }
    else        { in = inB + (size_t)(m - nA) * DIM * FDIM; out = outB + (size_t)(m - nA) * DIM * FDIM; }
    int tix = blockIdx.x;
    int rb = (tix % tiles_r) * 128;
    int cb = (tix / tiles_r) * 64;
    int t = threadIdx.x;
    // phase 1: read 2 rows x 16 cols, pack pairs, write LDS transposed
    int dp = t >> 2;              // row-pair 0..63
    int fc = (t & 3) * 16;        // col chunk
    const float* r0 = in + (size_t)(rb + 2 * dp) * C + cb + fc;
    const float* r1 = r0 + C;
#pragma unroll
    for (int j = 0; j < 16; j += 4) {
        float4 a = *(const float4*)(r0 + j);
        float4 b = *(const float4*)(r1 + j);
        sP[fc + j + 0][dp] = packh(a.x, b.x);
        sP[fc + j + 1][dp] = packh(a.y, b.y);
        sP[fc + j + 2][dp] = packh(a.z, b.z);
        sP[fc + j + 3][dp] = packh(a.w, b.w);
    }
    __syncthreads();
    // phase 2: each thread writes 32 contiguous f16 of one out-row
    int c = t >> 2;
    int rc = t & 3;
    uint4* dst = (uint4*)(out + (size_t)(cb + c) * R + rb + rc * 32);
    const unsigned* src = &sP[c][rc * 16];
#pragma unroll
    for (int j = 0; j < 4; j++)
        dst[j] = *(const uint4*)(src + j * 4);
}

// ---------------- Stage A: H = silu(x@Wg) * (x@Wu); all-f16, global_load_lds staging ----------------
// BM=128, BN=64 per weight, BK=32. LDS rows = 32 f16 = 4 chunks of 16B, chunk q of row r at pos (q+(r>>1))&3.
__global__ __launch_bounds__(256) void gateup_kernel(
    const f16_t* __restrict__ xf,
    const f16_t* __restrict__ wgT, const f16_t* __restrict__ wuT,
    const int* __restrict__ counts, const int* __restrict__ bucket,
    f16_t* __restrict__ H)
{
    int e = blockIdx.z;
    int cnt = counts[e * 32];
    int m0 = blockIdx.y * 128;
    if (m0 >= cnt) return;
    int n0 = blockIdx.x * 64;

    __shared__ f16_t sA[128 * 32];
    __shared__ f16_t sBg[64 * 32];
    __shared__ f16_t sBu[64 * 32];
    __shared__ int sEnt[128];

    int tid = threadIdx.x;
    if (tid < 128) {
        int i = m0 + tid;
        sEnt[tid] = bucket[e * N_TOK + (i < cnt ? i : m0)];
    }
    __syncthreads();

    int wave = tid >> 6, lane = tid & 63;
    int q = ((lane & 3) - (lane >> 3)) & 3;     // global-side chunk swizzle
    int rA0 = wave * 32 + (lane >> 2);
    int rA1 = rA0 + 16;
    int rB  = wave * 16 + (lane >> 2);
    const f16_t* gA0 = xf + (size_t)(sEnt[rA0] >> 1) * DIM + q * 8;
    const f16_t* gA1 = xf + (size_t)(sEnt[rA1] >> 1) * DIM + q * 8;
    const f16_t* gBg = wgT + ((size_t)e * FDIM + n0 + rB) * DIM + q * 8;
    const f16_t* gBu = wuT + ((size_t)e * FDIM + n0 + rB) * DIM + q * 8;
    f16_t* lA0 = &sA[wave * 1024 + lane * 8];
    f16_t* lA1 = lA0 + 512;
    f16_t* lBg = &sBg[wave * 512 + lane * 8];
    f16_t* lBu = &sBu[wave * 512 + lane * 8];

    f32x4 accG[4][2], accU[4][2];
    f32x4 zero = {0.f, 0.f, 0.f, 0.f};
#pragma unroll
    for (int i = 0; i < 4; i++)
#pragma unroll
        for (int j = 0; j < 2; j++) { accG[i][j] = zero; accU[i][j] = zero; }

    int wm = (wave & 1) * 64, wn = (wave >> 1) * 32;
    int fm = lane & 15, quad = lane >> 4;
    int p8 = ((quad + (fm >> 1)) & 3) * 8;      // swizzled chunk offset for frag reads

    for (int k0 = 0; k0 < DIM; k0 += 32) {
        gl2lds16(gA0 + k0, lA0);
        gl2lds16(gA1 + k0, lA1);
        gl2lds16(gBg + k0, lBg);
        gl2lds16(gBu + k0, lBu);
        __syncthreads();
        f16x8 af[4], bg[2], bu[2];
#pragma unroll
        for (int mi = 0; mi < 4; mi++)
            af[mi] = *(const f16x8*)&sA[(wm + mi * 16 + fm) * 32 + p8];
#pragma unroll
        for (int ni = 0; ni < 2; ni++) {
            bg[ni] = *(const f16x8*)&sBg[(wn + ni * 16 + fm) * 32 + p8];
            bu[ni] = *(const f16x8*)&sBu[(wn + ni * 16 + fm) * 32 + p8];
        }
#pragma unroll
        for (int mi = 0; mi < 4; mi++)
#pragma unroll
            for (int ni = 0; ni < 2; ni++) {
                accG[mi][ni] = __builtin_amdgcn_mfma_f32_16x16x32_f16(af[mi], bg[ni], accG[mi][ni], 0, 0, 0);
                accU[mi][ni] = __builtin_amdgcn_mfma_f32_16x16x32_f16(af[mi], bu[ni], accU[mi][ni], 0, 0, 0);
            }
        __syncthreads();
    }
    // epilogue: silu(G)*U -> H. C/D layout: col=lane&15, row=(lane>>4)*4+i
    int crow = quad * 4, ccol = fm;
#pragma unroll
    for (int mi = 0; mi < 4; mi++) {
#pragma unroll
        for (int i = 0; i < 4; i++) {
            int m = wm + mi * 16 + crow + i;
            if (m0 + m < cnt) {
                int ent = sEnt[m];
                f16_t* hr = H + (size_t)ent * FDIM + n0 + wn;
#pragma unroll
                for (int ni = 0; ni < 2; ni++) {
                    float g = accG[mi][ni][i], u = accU[mi][ni][i];
                    float h = (g / (1.f + __expf(-g))) * u;
                    hr[ni * 16 + ccol] = (f16_t)h;
                }
            }
        }
    }
}

// ---------------- Stage B: Y[ent,d] = w[ent] * (H[ent,:] @ Wd); 128x128, global_load_lds staging ----------------
__global__ __launch_bounds__(256) void down_kernel(
    const f16_t* __restrict__ H, const f16_t* __restrict__ wdT,
    const int* __restrict__ counts, const int* __restrict__ bucket,
    const float* __restrict__ topw, float* __restrict__ Y)
{
    int e = blockIdx.z;
    int cnt = counts[e * 32];
    int m0 = blockIdx.y * 128;
    if (m0 >= cnt) return;
    int n0 = blockIdx.x * 128;

    __shared__ f16_t sA[128 * 32];
    __shared__ f16_t sB[128 * 32];
    __shared__ int sEnt[128];

    int tid = threadIdx.x;
    if (tid < 128) {
        int i = m0 + tid;
        sEnt[tid] = bucket[e * N_TOK + (i < cnt ? i : m0)];
    }
    __syncthreads();

    int wave = tid >> 6, lane = tid & 63;
    int q = ((lane & 3) - (lane >> 3)) & 3;
    int r0 = wave * 32 + (lane >> 2);
    int r1 = r0 + 16;
    const f16_t* gA0 = H + (size_t)sEnt[r0] * FDIM + q * 8;
    const f16_t* gA1 = H + (size_t)sEnt[r1] * FDIM + q * 8;
    const f16_t* gB0 = wdT + ((size_t)e * DIM + n0 + r0) * FDIM + q * 8;
    const f16_t* gB1 = wdT + ((size_t)e * DIM + n0 + r1) * FDIM + q * 8;
    f16_t* lA0 = &sA[wave * 1024 + lane * 8];
    f16_t* lA1 = lA0 + 512;
    f16_t* lB0 = &sB[wave * 1024 + lane * 8];
    f16_t* lB1 = lB0 + 512;

    f32x4 acc[4][4];
    f32x4 zero = {0.f, 0.f, 0.f, 0.f};
#pragma unroll
    for (int i = 0; i < 4; i++)
#pragma unroll
        for (int j = 0; j < 4; j++) acc[i][j] = zero;

    int wm = (wave & 1) * 64, wn = (wave >> 1) * 64;
    int fm = lane & 15, quad = lane >> 4;
    int p8 = ((quad + (fm >> 1)) & 3) * 8;

    for (int k0 = 0; k0 < FDIM; k0 += 32) {
        gl2lds16(gA0 + k0, lA0);
        gl2lds16(gA1 + k0, lA1);
        gl2lds16(gB0 + k0, lB0);
        gl2lds16(gB1 + k0, lB1);
        __syncthreads();
        f16x8 af[4], bf[4];
#pragma unroll
        for (int mi = 0; mi < 4; mi++)
            af[mi] = *(const f16x8*)&sA[(wm + mi * 16 + fm) * 32 + p8];
#pragma unroll
        for (int ni = 0; ni < 4; ni++)
            bf[ni] = *(const f16x8*)&sB[(wn + ni * 16 + fm) * 32 + p8];
#pragma unroll
        for (int mi = 0; mi < 4; mi++)
#pragma unroll
            for (int ni = 0; ni < 4; ni++)
                acc[mi][ni] = __builtin_amdgcn_mfma_f32_16x16x32_f16(af[mi], bf[ni], acc[mi][ni], 0, 0, 0);
        __syncthreads();
    }
    int crow = quad * 4, ccol = fm;
#pragma unroll
    for (int mi = 0; mi < 4; mi++) {
#pragma unroll
        for (int i = 0; i < 4; i++) {
            int m = wm + mi * 16 + crow + i;
            if (m0 + m < cnt) {
                int ent = sEnt[m];
                float w = topw[ent];
                float* yr = Y + (size_t)ent * DIM + n0 + wn;
#pragma unroll
                for (int ni = 0; ni < 4; ni++)
                    yr[ni * 16 + ccol] = w * acc[mi][ni][i];
            }
        }
    }
}

// ---------------- Combine: out[t] = Y[2t] + Y[2t+1] ----------------
__global__ __launch_bounds__(256) void combine_kernel(
    const float* __restrict__ Y, float* __restrict__ out)
{
    int i = blockIdx.x * 256 + threadIdx.x;   // float4 index over [N_TOK][DIM/4]
    int t = i >> 8;
    int c = i & 255;
    float4 a = ((const float4*)Y)[(size_t)(2 * t) * 256 + c];
    float4 b = ((const float4*)Y)[(size_t)(2 * t + 1) * 256 + c];
    float4 o;
    o.x = a.x + b.x; o.y = a.y + b.y; o.z = a.z + b.z; o.w = a.w + b.w;
    ((float4*)out)[i] = o;
}

extern "C" void kernel_launch(void* const* d_in, const int* in_sizes, int n_in,
                              void* d_out, int out_size, void* d_ws, size_t ws_size,
                              hipStream_t stream) {
    const float* x  = (const float*)d_in[0];
    const float* wr = (const float*)d_in[1];
    const float* wg = (const float*)d_in[2];
    const float* wu = (const float*)d_in[3];
    const float* wd = (const float*)d_in[4];
    float* out = (float*)d_out;
    char* ws = (char*)d_ws;
    const size_t MB = 1ull << 20;

    // liveness-aliased workspace plan (peak 105 MB):
    int*   counts = (int*)ws;                       // 1 KB (8 counters @ 128 B stride)
    int*   bucket = (int*)(ws + 1024);              // 128 KB
    float* topw   = (float*)(ws + 160 * 1024);      // 32 KB
    f16_t* xf     = (f16_t*)(ws + 1 * MB);          // 1..9 MB   (dead after gateup)
    f16_t* wgT    = (f16_t*)(ws + 9 * MB);          // 9..41 MB  (dead after gateup)
    f16_t* wuT    = (f16_t*)(ws + 41 * MB);         // 41..73 MB (dead after gateup)
    f16_t* H      = (f16_t*)(ws + 73 * MB);         // 73..105 MB
    f16_t* wdT    = (f16_t*)(ws + 1 * MB);          // alias 1..33 MB (written post-gateup)
    float* Y      = (float*)(ws + 33 * MB);         // alias 33..65 MB (written by down)

    hipMemsetAsync(counts, 0, 1024, stream);
    router_kernel<<<256, 256, 0, stream>>>(x, wr, topw, counts, bucket);
    xcast_kernel<<<2048, 256, 0, stream>>>(x, xf);
    // Wg, Wu: [1024][2048] -> [2048][1024]; 256 tiles each, 16 matrices
    transpose_cvt<<<dim3(256, 16), 256, 0, stream>>>(wg, wu, wgT, wuT, DIM, FDIM, DIM / 128, NEXP);
    gateup_kernel<<<dim3(FDIM / 64, 32, NEXP), 256, 0, stream>>>(xf, wgT, wuT, counts, bucket, H);
    // Wd: [2048][1024] -> [1024][2048]; 256 tiles, 8 matrices (into dead xf/wgT region)
    transpose_cvt<<<dim3(256, 8), 256, 0, stream>>>(wd, wd, wdT, wdT, FDIM, DIM, FDIM / 128, NEXP);
    down_kernel<<<dim3(DIM / 128, 32, NEXP), 256, 0, stream>>>(H, wdT, counts, bucket, topw, Y);
    combine_kernel<<<4096, 256, 0, stream>>>(Y, out);
}